// Round 3
// baseline (346.777 us; speedup 1.0000x reference)
//
#include <hip/hip_runtime.h>
#include <hip/hip_bf16.h>

#define NEG_SLOPE 0.2f
#define GGRP 128
#define TOUT 10

// ---------------------------------------------------------------------------
// init: zero degree array, set pool accumulator to -inf
// ---------------------------------------------------------------------------
__global__ void init_kernel(int* __restrict__ deg, float* __restrict__ gpool,
                            int n, int gsize) {
    int i = blockIdx.x * blockDim.x + threadIdx.x;
    if (i < n) deg[i] = 0;
    if (i < gsize) gpool[i] = -__builtin_inff();
}

// ---------------------------------------------------------------------------
// degree: count incoming edges per dst
// ---------------------------------------------------------------------------
__global__ void degree_kernel(const int* __restrict__ dst, int* __restrict__ deg, int E) {
    int e = blockIdx.x * blockDim.x + threadIdx.x;
    if (e < E) atomicAdd(&deg[dst[e]], 1);
}

// ---------------------------------------------------------------------------
// hierarchical scan: A) per-block exclusive scan + block sums
// ---------------------------------------------------------------------------
__global__ __launch_bounds__(256)
void scanA_kernel(const int* __restrict__ deg, int* __restrict__ rowptr,
                  int* __restrict__ bsum, int n) {
    __shared__ int wsum[4];
    int tid = threadIdx.x, lane = tid & 63, wid = tid >> 6;
    int idx = blockIdx.x * 256 + tid;
    int v = (idx < n) ? deg[idx] : 0;
    int x = v;
    #pragma unroll
    for (int off = 1; off < 64; off <<= 1) {
        int t = __shfl_up(x, off, 64);
        if (lane >= off) x += t;
    }
    if (lane == 63) wsum[wid] = x;
    __syncthreads();
    if (tid == 0) {
        int s = 0;
        #pragma unroll
        for (int i = 0; i < 4; ++i) { int t = wsum[i]; wsum[i] = s; s += t; }
        bsum[blockIdx.x] = s;
    }
    __syncthreads();
    int excl = x - v + wsum[wid];
    if (idx < n) rowptr[idx] = excl;
}

// B) single-wave scan of block sums (nb <= 128)
__global__ void scanB_kernel(const int* __restrict__ bsum, int* __restrict__ boff,
                             int* __restrict__ rowptr, int n, int nb) {
    int lane = threadIdx.x;           // 64 threads
    int v0 = (lane < nb) ? bsum[lane] : 0;
    int v1 = (64 + lane < nb) ? bsum[64 + lane] : 0;
    int s0 = v0, s1 = v1;
    #pragma unroll
    for (int off = 1; off < 64; off <<= 1) {
        int t0 = __shfl_up(s0, off, 64);
        int t1 = __shfl_up(s1, off, 64);
        if (lane >= off) { s0 += t0; s1 += t1; }
    }
    int tot0 = __shfl(s0, 63, 64);
    s1 += tot0;
    boff[lane] = s0 - v0;
    boff[64 + lane] = s1 - v1;
    if (lane == 63) rowptr[n] = s1;   // grand total
}

// C) apply block offsets, fill cursor
__global__ void scanC_kernel(int* __restrict__ rowptr, int* __restrict__ cursor,
                             const int* __restrict__ boff, int n) {
    int idx = blockIdx.x * blockDim.x + threadIdx.x;
    if (idx < n) {
        int r = rowptr[idx] + boff[idx >> 8];
        rowptr[idx] = r;
        cursor[idx] = r;
    }
}

// ---------------------------------------------------------------------------
// scatter edges into CSR slots (by dst)
// ---------------------------------------------------------------------------
__global__ void scatter_kernel(const int* __restrict__ src, const int* __restrict__ dst,
                               int* __restrict__ cursor, int* __restrict__ csr, int E) {
    int e = blockIdx.x * blockDim.x + threadIdx.x;
    if (e < E) {
        int slot = atomicAdd(&cursor[dst[e]], 1);
        csr[slot] = src[e];
    }
}

// ---------------------------------------------------------------------------
// xl/xr GEMM, single-barrier form.
// Block tile: 32 rows x 64 cols, full K staged once.
// colBlk 0,1 -> Wl cols 0/64 ; colBlk 2,3 -> Wr cols 0/64.
// Thread: 8 rows x 1 col, acc in regs. One __syncthreads total.
// ---------------------------------------------------------------------------
template <int FIN>
__global__ __launch_bounds__(256)
void gemm_xlxr_kernel(const float* __restrict__ X,
                      const float* __restrict__ Wl, const float* __restrict__ bl,
                      const float* __restrict__ Wr, const float* __restrict__ br,
                      float* __restrict__ xl, float* __restrict__ xr, int n) {
    constexpr int KP = FIN + 4;          // pad: stride 4 mod 32 -> b128 floor
    __shared__ float Ws[64][KP];
    __shared__ float Xs[32][KP];
    int tid = threadIdx.x;
    int nRowBlk = (n + 31) >> 5;
    int rowBlk = blockIdx.x % nRowBlk;
    int colBlk = blockIdx.x / nRowBlk;   // 0..3
    const float* Wbase = (colBlk < 2) ? Wl : Wr;
    const float* bbase = (colBlk < 2) ? bl : br;
    float*       obase = (colBlk < 2) ? xl : xr;
    int cOff = (colBlk & 1) * 64;
    int row0 = rowBlk * 32;

    // stage W-tile: rows cOff..cOff+63, all K (contiguous, coalesced)
    for (int idx = tid * 4; idx < 64 * FIN; idx += 1024) {
        int r = idx / FIN, k = idx % FIN;
        *(float4*)&Ws[r][k] = *(const float4*)&Wbase[(cOff + r) * FIN + k];
    }
    // stage X-tile: rows row0..row0+31
    for (int idx = tid * 4; idx < 32 * FIN; idx += 1024) {
        int r = idx / FIN, k = idx % FIN;
        int gr = row0 + r;
        float4 v = {0.f, 0.f, 0.f, 0.f};
        if (gr < n) v = *(const float4*)&X[(size_t)gr * FIN + k];
        *(float4*)&Xs[r][k] = v;
    }
    __syncthreads();

    int cc = tid & 63;       // col within tile (one wave spans all 64 cols)
    int rg = tid >> 6;       // 0..3 -> rows rg*8 .. rg*8+7
    float acc[8] = {0.f, 0.f, 0.f, 0.f, 0.f, 0.f, 0.f, 0.f};
    #pragma unroll 4
    for (int k = 0; k < FIN; k += 4) {
        float4 w4 = *(const float4*)&Ws[cc][k];
        #pragma unroll
        for (int j = 0; j < 8; ++j) {
            float4 x4 = *(const float4*)&Xs[rg * 8 + j][k];
            acc[j] = fmaf(x4.x, w4.x, acc[j]);
            acc[j] = fmaf(x4.y, w4.y, acc[j]);
            acc[j] = fmaf(x4.z, w4.z, acc[j]);
            acc[j] = fmaf(x4.w, w4.w, acc[j]);
        }
    }
    float bv = bbase[cOff + cc];
    #pragma unroll
    for (int j = 0; j < 8; ++j) {
        int gr = row0 + rg * 8 + j;
        if (gr < n) obase[(size_t)gr * 128 + cOff + cc] = acc[j] + bv;
    }
}

// ---------------------------------------------------------------------------
// Fused GATv2 conv + Linear(HD->D).
// One wave per node; 2 edges in flight (32 lanes / edge, float4 per lane);
// depth-2 software prefetch of csr + xl rows.
// Single-pass softmax (no max subtraction: |alpha| small, exp safe).
// Epilogue: conv-out -> LDS slot -> y = out @ lw.T + lb (fused).
// ---------------------------------------------------------------------------
__global__ __launch_bounds__(256)
void gat_fused_kernel(const float* __restrict__ xl, const float* __restrict__ xr,
                      const float* __restrict__ att, const float* __restrict__ cb,
                      const float* __restrict__ lw, const float* __restrict__ lb,
                      const int* __restrict__ rowptr, const int* __restrict__ csr,
                      float* __restrict__ out /*[n][32]*/, int n) {
    __shared__ float lws[32][132];     // lw staged, pad 132
    __shared__ float oslot[4][128];    // per-wave conv-out vector
    int tid = threadIdx.x;
    #pragma unroll
    for (int i = 0; i < 16; ++i) {
        int idx = tid + i * 256;       // 4096 = 32*128
        lws[idx >> 7][idx & 127] = lw[idx];
    }
    __syncthreads();

    int wid = tid >> 6, lane = tid & 63;
    int nd = blockIdx.x * 4 + wid;
    if (nd >= n) return;
    int half = lane >> 5;              // which edge of the pair
    int l32 = lane & 31;
    int f4 = l32 * 4;                  // features f4..f4+3 (head = l32>>3)

    const float4 xr4  = *(const float4*)(xr + (size_t)nd * 128 + f4);
    const float4 at4  = *(const float4*)(att + f4);
    const float4 xls4 = *(const float4*)(xl + (size_t)nd * 128 + f4);

    int start = rowptr[nd], end = rowptr[nd + 1];

    // self-loop (counted once, on half 0)
    float den;
    float4 acc;
    {
        float e0 = xls4.x + xr4.x; e0 = e0 > 0.f ? e0 : NEG_SLOPE * e0;
        float e1 = xls4.y + xr4.y; e1 = e1 > 0.f ? e1 : NEG_SLOPE * e1;
        float e2 = xls4.z + xr4.z; e2 = e2 > 0.f ? e2 : NEG_SLOPE * e2;
        float e3 = xls4.w + xr4.w; e3 = e3 > 0.f ? e3 : NEG_SLOPE * e3;
        float q = e0 * at4.x + e1 * at4.y + e2 * at4.z + e3 * at4.w;
        q += __shfl_xor(q, 1); q += __shfl_xor(q, 2); q += __shfl_xor(q, 4);
        float a = __expf(q);
        if (half == 0) {
            den = a;
            acc.x = a * xls4.x; acc.y = a * xls4.y;
            acc.z = a * xls4.z; acc.w = a * xls4.w;
        } else {
            den = 0.f; acc.x = acc.y = acc.z = acc.w = 0.f;
        }
    }

    // edges: half h takes i = start+h, start+h+2, ...
    // depth-2 pipeline: csr prefetched 2 iters ahead, xl row 1 iter ahead.
    int i = start + half;
    int sA = (i < end) ? csr[i] : 0;
    int sB = (i + 2 < end) ? csr[i + 2] : 0;
    float4 xvA = {0.f, 0.f, 0.f, 0.f};
    if (i < end) xvA = *(const float4*)(xl + (size_t)sA * 128 + f4);
    for (; i < end; i += 2) {
        float4 xv = xvA;
        sA = sB;
        if (i + 4 < end) sB = csr[i + 4];
        if (i + 2 < end) xvA = *(const float4*)(xl + (size_t)sA * 128 + f4);
        float e0 = xv.x + xr4.x; e0 = e0 > 0.f ? e0 : NEG_SLOPE * e0;
        float e1 = xv.y + xr4.y; e1 = e1 > 0.f ? e1 : NEG_SLOPE * e1;
        float e2 = xv.z + xr4.z; e2 = e2 > 0.f ? e2 : NEG_SLOPE * e2;
        float e3 = xv.w + xr4.w; e3 = e3 > 0.f ? e3 : NEG_SLOPE * e3;
        float q = e0 * at4.x + e1 * at4.y + e2 * at4.z + e3 * at4.w;
        q += __shfl_xor(q, 1); q += __shfl_xor(q, 2); q += __shfl_xor(q, 4);
        float a = __expf(q);
        den += a;
        acc.x = fmaf(a, xv.x, acc.x);
        acc.y = fmaf(a, xv.y, acc.y);
        acc.z = fmaf(a, xv.z, acc.z);
        acc.w = fmaf(a, xv.w, acc.w);
    }

    // combine the two halves
    acc.x += __shfl_xor(acc.x, 32);
    acc.y += __shfl_xor(acc.y, 32);
    acc.z += __shfl_xor(acc.z, 32);
    acc.w += __shfl_xor(acc.w, 32);
    den   += __shfl_xor(den, 32);

    float inv = 1.0f / (den * (float)(end - start + 1));
    const float4 cb4 = *(const float4*)(cb + f4);
    float4 o;
    o.x = fmaf(acc.x, inv, cb4.x);
    o.y = fmaf(acc.y, inv, cb4.y);
    o.z = fmaf(acc.z, inv, cb4.z);
    o.w = fmaf(acc.w, inv, cb4.w);

    if (half == 0) *(float4*)&oslot[wid][f4] = o;
    asm volatile("s_waitcnt lgkmcnt(0)" ::: "memory");

    // fused linear: y[c] = sum_k o[k]*lw[c][k]; c=l32, k-range split by half
    float y = 0.f;
    int kbase = half * 64;
    #pragma unroll
    for (int k = 0; k < 64; k += 4) {
        float4 lv = *(const float4*)&lws[l32][kbase + k];
        float4 ov = *(const float4*)&oslot[wid][kbase + k];
        y = fmaf(lv.x, ov.x, y);
        y = fmaf(lv.y, ov.y, y);
        y = fmaf(lv.z, ov.z, y);
        y = fmaf(lv.w, ov.w, y);
    }
    y += __shfl_xor(y, 32);
    if (half == 0) out[(size_t)nd * 32 + l32] = y + lb[l32];
}

// ---------------------------------------------------------------------------
// global max pool over sorted batch ids (run-length + atomic flush)
// ---------------------------------------------------------------------------
__device__ __forceinline__ void atomicMaxFloat(float* addr, float val) {
    if (val >= 0.f) atomicMax((int*)addr, __float_as_int(val));
    else atomicMin((unsigned int*)addr, (unsigned int)__float_as_int(val));
}

__global__ void pool_kernel(const float* __restrict__ H, const int* __restrict__ batch,
                            float* __restrict__ g, int n) {
    int tid = threadIdx.x;
    int dim = tid & 31;
    int sub = tid >> 5;                 // 0..7
    int nodeStart = blockIdx.x * 128 + sub * 16;
    float m = -__builtin_inff();
    int cur = -1;
    for (int j = 0; j < 16; ++j) {
        int nd = nodeStart + j;
        if (nd >= n) break;
        int b = batch[nd];
        if (b != cur) {
            if (cur >= 0) atomicMaxFloat(&g[cur * 32 + dim], m);
            cur = b; m = -__builtin_inff();
        }
        m = fmaxf(m, H[nd * 32 + dim]);
    }
    if (cur >= 0) atomicMaxFloat(&g[cur * 32 + dim], m);
}

// ---------------------------------------------------------------------------
// final MLP: out = relu(g@fc1.T+b1) @ fc2.T + b2   (single block)
// ---------------------------------------------------------------------------
__global__ __launch_bounds__(256)
void fc_kernel(const float* __restrict__ g,
               const float* __restrict__ fc1W, const float* __restrict__ fc1b,
               const float* __restrict__ fc2W, const float* __restrict__ fc2b,
               float* __restrict__ out) {
    __shared__ float g1[GGRP * 32];
    int tid = threadIdx.x;
    for (int idx = tid; idx < GGRP * 32; idx += 256) {
        int r = idx >> 5, c = idx & 31;
        float acc = fc1b[c];
        #pragma unroll
        for (int k = 0; k < 32; ++k) acc = fmaf(g[r * 32 + k], fc1W[c * 32 + k], acc);
        g1[idx] = acc > 0.f ? acc : 0.f;
    }
    __syncthreads();
    for (int idx = tid; idx < GGRP * TOUT; idx += 256) {
        int r = idx / TOUT, c = idx - r * TOUT;
        float acc = fc2b[c];
        #pragma unroll
        for (int k = 0; k < 32; ++k) acc = fmaf(g1[r * 32 + k], fc2W[c * 32 + k], acc);
        out[idx] = acc;
    }
}

// ---------------------------------------------------------------------------
extern "C" void kernel_launch(void* const* d_in, const int* in_sizes, int n_in,
                              void* d_out, int out_size, void* d_ws, size_t ws_size,
                              hipStream_t stream) {
    const float* x     = (const float*)d_in[0];
    const int*   ei    = (const int*)d_in[1];     // [2][E]
    const int*   batch = (const int*)d_in[2];
    const float* Wl0 = (const float*)d_in[3];
    const float* bl0 = (const float*)d_in[4];
    const float* Wr0 = (const float*)d_in[5];
    const float* br0 = (const float*)d_in[6];
    const float* at0 = (const float*)d_in[7];
    const float* cb0 = (const float*)d_in[8];
    const float* lw0 = (const float*)d_in[9];
    const float* lb0 = (const float*)d_in[10];
    const float* Wl1 = (const float*)d_in[11];
    const float* bl1 = (const float*)d_in[12];
    const float* Wr1 = (const float*)d_in[13];
    const float* br1 = (const float*)d_in[14];
    const float* at1 = (const float*)d_in[15];
    const float* cb1 = (const float*)d_in[16];
    const float* lw1 = (const float*)d_in[17];
    const float* lb1 = (const float*)d_in[18];
    const float* fc1W = (const float*)d_in[19];
    const float* fc1b = (const float*)d_in[20];
    const float* fc2W = (const float*)d_in[21];
    const float* fc2b = (const float*)d_in[22];

    const int n = in_sizes[0] / 128;      // 30000
    const int E = in_sizes[1] / 2;        // 480000
    const int* src = ei;
    const int* dst = ei + E;
    const int nblkScan = (n + 255) / 256; // 118
    const int nRowBlk = (n + 31) / 32;    // 938

    // workspace layout
    size_t off = 0;
    auto alloc = [&](size_t bytes) {
        void* p = (char*)d_ws + off;
        off += (bytes + 255) & ~(size_t)255;
        return p;
    };
    float* xl    = (float*)alloc((size_t)n * 128 * 4);
    float* xr    = (float*)alloc((size_t)n * 128 * 4);
    float* hbuf  = (float*)alloc((size_t)n * 32 * 4);
    int* deg     = (int*)alloc((size_t)n * 4);
    int* rowptr  = (int*)alloc((size_t)(n + 1) * 4);
    int* cursor  = (int*)alloc((size_t)n * 4);
    int* csr     = (int*)alloc((size_t)E * 4);
    int* bsum    = (int*)alloc(128 * 4);
    int* boff    = (int*)alloc(128 * 4);
    float* gpool = (float*)alloc((size_t)GGRP * 32 * 4);

    // graph structure (shared by both convs)
    init_kernel<<<(n + 255) / 256, 256, 0, stream>>>(deg, gpool, n, GGRP * 32);
    degree_kernel<<<(E + 255) / 256, 256, 0, stream>>>(dst, deg, E);
    scanA_kernel<<<nblkScan, 256, 0, stream>>>(deg, rowptr, bsum, n);
    scanB_kernel<<<1, 64, 0, stream>>>(bsum, boff, rowptr, n, nblkScan);
    scanC_kernel<<<nblkScan, 256, 0, stream>>>(rowptr, cursor, boff, n);
    scatter_kernel<<<(E + 255) / 256, 256, 0, stream>>>(src, dst, cursor, csr, E);

    // conv 0 (fused conv+linear)
    gemm_xlxr_kernel<128><<<4 * nRowBlk, 256, 0, stream>>>(x, Wl0, bl0, Wr0, br0, xl, xr, n);
    gat_fused_kernel<<<(n + 3) / 4, 256, 0, stream>>>(xl, xr, at0, cb0, lw0, lb0,
                                                      rowptr, csr, hbuf, n);
    // conv 1
    gemm_xlxr_kernel<32><<<4 * nRowBlk, 256, 0, stream>>>(hbuf, Wl1, bl1, Wr1, br1, xl, xr, n);
    gat_fused_kernel<<<(n + 3) / 4, 256, 0, stream>>>(xl, xr, at1, cb1, lw1, lb1,
                                                      rowptr, csr, hbuf, n);

    // pool + MLP
    pool_kernel<<<(n + 127) / 128, 256, 0, stream>>>(hbuf, batch, gpool, n);
    fc_kernel<<<1, 256, 0, stream>>>(gpool, fc1W, fc1b, fc2W, fc2b, (float*)d_out);
}

// Round 4
// 311.668 us; speedup vs baseline: 1.1127x; 1.1127x over previous
//
#include <hip/hip_runtime.h>
#include <hip/hip_bf16.h>

#define NEG_SLOPE 0.2f
#define GGRP 128
#define TOUT 10

// ---------------------------------------------------------------------------
// init: zero degree array, set pool accumulator to -inf
// ---------------------------------------------------------------------------
__global__ void init_kernel(int* __restrict__ deg, float* __restrict__ gpool,
                            int n, int gsize) {
    int i = blockIdx.x * blockDim.x + threadIdx.x;
    if (i < n) deg[i] = 0;
    if (i < gsize) gpool[i] = -__builtin_inff();
}

// ---------------------------------------------------------------------------
// degree: count incoming edges per dst
// ---------------------------------------------------------------------------
__global__ void degree_kernel(const int* __restrict__ dst, int* __restrict__ deg, int E) {
    int e = blockIdx.x * blockDim.x + threadIdx.x;
    if (e < E) atomicAdd(&deg[dst[e]], 1);
}

// ---------------------------------------------------------------------------
// hierarchical scan: A) per-block exclusive scan + block sums
// ---------------------------------------------------------------------------
__global__ __launch_bounds__(256)
void scanA_kernel(const int* __restrict__ deg, int* __restrict__ rowptr,
                  int* __restrict__ bsum, int n) {
    __shared__ int wsum[4];
    int tid = threadIdx.x, lane = tid & 63, wid = tid >> 6;
    int idx = blockIdx.x * 256 + tid;
    int v = (idx < n) ? deg[idx] : 0;
    int x = v;
    #pragma unroll
    for (int off = 1; off < 64; off <<= 1) {
        int t = __shfl_up(x, off, 64);
        if (lane >= off) x += t;
    }
    if (lane == 63) wsum[wid] = x;
    __syncthreads();
    if (tid == 0) {
        int s = 0;
        #pragma unroll
        for (int i = 0; i < 4; ++i) { int t = wsum[i]; wsum[i] = s; s += t; }
        bsum[blockIdx.x] = s;
    }
    __syncthreads();
    int excl = x - v + wsum[wid];
    if (idx < n) rowptr[idx] = excl;
}

// B) single-wave scan of block sums (nb <= 128)
__global__ void scanB_kernel(const int* __restrict__ bsum, int* __restrict__ boff,
                             int* __restrict__ rowptr, int n, int nb) {
    int lane = threadIdx.x;           // 64 threads
    int v0 = (lane < nb) ? bsum[lane] : 0;
    int v1 = (64 + lane < nb) ? bsum[64 + lane] : 0;
    int s0 = v0, s1 = v1;
    #pragma unroll
    for (int off = 1; off < 64; off <<= 1) {
        int t0 = __shfl_up(s0, off, 64);
        int t1 = __shfl_up(s1, off, 64);
        if (lane >= off) { s0 += t0; s1 += t1; }
    }
    int tot0 = __shfl(s0, 63, 64);
    s1 += tot0;
    boff[lane] = s0 - v0;
    boff[64 + lane] = s1 - v1;
    if (lane == 63) rowptr[n] = s1;   // grand total
}

// C) apply block offsets, fill cursor
__global__ void scanC_kernel(int* __restrict__ rowptr, int* __restrict__ cursor,
                             const int* __restrict__ boff, int n) {
    int idx = blockIdx.x * blockDim.x + threadIdx.x;
    if (idx < n) {
        int r = rowptr[idx] + boff[idx >> 8];
        rowptr[idx] = r;
        cursor[idx] = r;
    }
}

// ---------------------------------------------------------------------------
// scatter edges into CSR slots (by dst)
// ---------------------------------------------------------------------------
__global__ void scatter_kernel(const int* __restrict__ src, const int* __restrict__ dst,
                               int* __restrict__ cursor, int* __restrict__ csr, int E) {
    int e = blockIdx.x * blockDim.x + threadIdx.x;
    if (e < E) {
        int slot = atomicAdd(&cursor[dst[e]], 1);
        csr[slot] = src[e];
    }
}

// ---------------------------------------------------------------------------
// Register-blocked GEMM: OUT[r][c] = sum_k X[r][k] * W[c][k] + b[c]
// Block tile 128 rows x 128 cols (one W matrix; grid.y-like split via blockIdx),
// BK=32, LDS staged transposed [BK][BM+4], thread tile 8x8 (64 acc VGPR).
// Chunk-level global->reg->LDS prefetch: loads for chunk c+1 issue before
// compute of chunk c (T14 async-stage split).
// ---------------------------------------------------------------------------
template <int FIN>
__global__ __launch_bounds__(256, 2)
void gemm_tile_kernel(const float* __restrict__ X,
                      const float* __restrict__ Wl, const float* __restrict__ bl,
                      const float* __restrict__ Wr, const float* __restrict__ br,
                      float* __restrict__ xl, float* __restrict__ xr,
                      int n, int nRowBlk) {
    constexpr int BK = 32, BM = 128, LDA = BM + 4;
    constexpr int NCHUNK = FIN / BK;
    __shared__ float Xs[BK][LDA];
    __shared__ float Ws[BK][LDA];
    int tid = threadIdx.x;
    int rowBlk = blockIdx.x;
    int colBlk = 0;
    if (rowBlk >= nRowBlk) { rowBlk -= nRowBlk; colBlk = 1; }
    const float* __restrict__ Wb = colBlk ? Wr : Wl;
    const float* __restrict__ bb = colBlk ? br : bl;
    float* __restrict__ ob = colBlk ? xr : xl;
    int row0 = rowBlk * BM;

    // staging map: thread covers rows sr, sr+32, sr+64, sr+96 at k-quad skq
    int sr  = tid >> 3;          // 0..31
    int skq = (tid & 7) * 4;     // 0,4,..,28

    float4 xpre[4], wpre[4];

    auto load_pre = [&](int c) {
        int k0 = c * BK;
        #pragma unroll
        for (int i = 0; i < 4; ++i) {
            int r = sr + i * 32;
            int gr = row0 + r;
            float4 v = {0.f, 0.f, 0.f, 0.f};
            if (gr < n) v = *(const float4*)&X[(size_t)gr * FIN + k0 + skq];
            xpre[i] = v;
            wpre[i] = *(const float4*)&Wb[(size_t)r * FIN + k0 + skq];
        }
    };
    auto store_pre = [&]() {
        #pragma unroll
        for (int i = 0; i < 4; ++i) {
            int r = sr + i * 32;
            Xs[skq + 0][r] = xpre[i].x; Xs[skq + 1][r] = xpre[i].y;
            Xs[skq + 2][r] = xpre[i].z; Xs[skq + 3][r] = xpre[i].w;
            Ws[skq + 0][r] = wpre[i].x; Ws[skq + 1][r] = wpre[i].y;
            Ws[skq + 2][r] = wpre[i].z; Ws[skq + 3][r] = wpre[i].w;
        }
    };

    load_pre(0);
    store_pre();
    __syncthreads();

    int tx = tid & 15;           // col group: cols tx*8 .. tx*8+7
    int ty = tid >> 4;           // row group: rows ty*8 .. ty*8+7
    float acc[8][8];
    #pragma unroll
    for (int i = 0; i < 8; ++i)
        #pragma unroll
        for (int j = 0; j < 8; ++j) acc[i][j] = 0.f;

    #pragma unroll
    for (int c = 0; c < NCHUNK; ++c) {
        if (c + 1 < NCHUNK) load_pre(c + 1);   // issue early, hide under compute
        #pragma unroll 8
        for (int k = 0; k < BK; ++k) {
            float4 a0 = *(const float4*)&Xs[k][ty * 8];
            float4 a1 = *(const float4*)&Xs[k][ty * 8 + 4];
            float4 b0 = *(const float4*)&Ws[k][tx * 8];
            float4 b1 = *(const float4*)&Ws[k][tx * 8 + 4];
            float av[8] = {a0.x, a0.y, a0.z, a0.w, a1.x, a1.y, a1.z, a1.w};
            float bv[8] = {b0.x, b0.y, b0.z, b0.w, b1.x, b1.y, b1.z, b1.w};
            #pragma unroll
            for (int i = 0; i < 8; ++i)
                #pragma unroll
                for (int j = 0; j < 8; ++j)
                    acc[i][j] = fmaf(av[i], bv[j], acc[i][j]);
        }
        if (c + 1 < NCHUNK) {
            __syncthreads();     // all reads of chunk c done
            store_pre();
            __syncthreads();     // chunk c+1 visible
        }
    }

    float bias[8];
    #pragma unroll
    for (int j = 0; j < 8; ++j) bias[j] = bb[tx * 8 + j];
    #pragma unroll
    for (int i = 0; i < 8; ++i) {
        int gr = row0 + ty * 8 + i;
        if (gr < n) {
            float4 o0, o1;
            o0.x = acc[i][0] + bias[0]; o0.y = acc[i][1] + bias[1];
            o0.z = acc[i][2] + bias[2]; o0.w = acc[i][3] + bias[3];
            o1.x = acc[i][4] + bias[4]; o1.y = acc[i][5] + bias[5];
            o1.z = acc[i][6] + bias[6]; o1.w = acc[i][7] + bias[7];
            *(float4*)&ob[(size_t)gr * 128 + tx * 8]     = o0;
            *(float4*)&ob[(size_t)gr * 128 + tx * 8 + 4] = o1;
        }
    }
}

// ---------------------------------------------------------------------------
// Fused GATv2 conv + Linear(HD->D).
// One wave per node; 4 edges in flight (16 lanes / edge, 8 floats per lane);
// depth-2 software prefetch of csr + xl rows (up to ~4 rows / 8 loads live).
// Single-pass softmax (no max subtraction: |alpha| small, exp safe).
// Head = 4 lanes now -> 2-shfl reduction.
// Epilogue: conv-out -> LDS slot -> y = out @ lw.T + lb (fused).
// ---------------------------------------------------------------------------
__global__ __launch_bounds__(256)
void gat_fused_kernel(const float* __restrict__ xl, const float* __restrict__ xr,
                      const float* __restrict__ att, const float* __restrict__ cb,
                      const float* __restrict__ lw, const float* __restrict__ lb,
                      const int* __restrict__ rowptr, const int* __restrict__ csr,
                      float* __restrict__ out /*[n][32]*/, int n) {
    __shared__ float lws[32][132];     // lw staged, pad 132
    __shared__ float oslot[4][128];    // per-wave conv-out vector
    int tid = threadIdx.x;
    #pragma unroll
    for (int i = 0; i < 16; ++i) {
        int idx = tid + i * 256;       // 4096 = 32*128
        lws[idx >> 7][idx & 127] = lw[idx];
    }
    __syncthreads();

    int wid = tid >> 6, lane = tid & 63;
    int nd = blockIdx.x * 4 + wid;
    if (nd >= n) return;
    int q4  = lane >> 4;               // edge slot 0..3
    int l16 = lane & 15;
    int f8  = l16 * 8;                 // features f8..f8+7 (head = l16>>2)

    const float4 xrA  = *(const float4*)(xr + (size_t)nd * 128 + f8);
    const float4 xrB  = *(const float4*)(xr + (size_t)nd * 128 + f8 + 4);
    const float4 atA  = *(const float4*)(att + f8);
    const float4 atB  = *(const float4*)(att + f8 + 4);
    const float4 xlsA = *(const float4*)(xl + (size_t)nd * 128 + f8);
    const float4 xlsB = *(const float4*)(xl + (size_t)nd * 128 + f8 + 4);

    int start = rowptr[nd], end = rowptr[nd + 1];

    float den;
    float accA[4] = {0.f, 0.f, 0.f, 0.f};
    float accB[4] = {0.f, 0.f, 0.f, 0.f};

    // self-loop (counted once, on slot 0)
    {
        float e0 = xlsA.x + xrA.x; e0 = e0 > 0.f ? e0 : NEG_SLOPE * e0;
        float e1 = xlsA.y + xrA.y; e1 = e1 > 0.f ? e1 : NEG_SLOPE * e1;
        float e2 = xlsA.z + xrA.z; e2 = e2 > 0.f ? e2 : NEG_SLOPE * e2;
        float e3 = xlsA.w + xrA.w; e3 = e3 > 0.f ? e3 : NEG_SLOPE * e3;
        float e4 = xlsB.x + xrB.x; e4 = e4 > 0.f ? e4 : NEG_SLOPE * e4;
        float e5 = xlsB.y + xrB.y; e5 = e5 > 0.f ? e5 : NEG_SLOPE * e5;
        float e6 = xlsB.z + xrB.z; e6 = e6 > 0.f ? e6 : NEG_SLOPE * e6;
        float e7 = xlsB.w + xrB.w; e7 = e7 > 0.f ? e7 : NEG_SLOPE * e7;
        float q = e0 * atA.x + e1 * atA.y + e2 * atA.z + e3 * atA.w
                + e4 * atB.x + e5 * atB.y + e6 * atB.z + e7 * atB.w;
        q += __shfl_xor(q, 1); q += __shfl_xor(q, 2);   // head = 4 lanes
        float a = __expf(q);
        if (q4 == 0) {
            den = a;
            accA[0] = a * xlsA.x; accA[1] = a * xlsA.y;
            accA[2] = a * xlsA.z; accA[3] = a * xlsA.w;
            accB[0] = a * xlsB.x; accB[1] = a * xlsB.y;
            accB[2] = a * xlsB.z; accB[3] = a * xlsB.w;
        } else {
            den = 0.f;
        }
    }

    // edges: slot q takes i = start+q, start+q+4, ...
    int i = start + q4;
    int sA = (i < end) ? csr[i] : 0;
    int sB = (i + 4 < end) ? csr[i + 4] : 0;
    float4 pre0 = {0.f, 0.f, 0.f, 0.f}, pre1 = pre0;
    if (i < end) {
        pre0 = *(const float4*)(xl + (size_t)sA * 128 + f8);
        pre1 = *(const float4*)(xl + (size_t)sA * 128 + f8 + 4);
    }
    for (; i < end; i += 4) {
        float4 x0 = pre0, x1 = pre1;
        sA = sB;
        if (i + 8 < end) sB = csr[i + 8];
        if (i + 4 < end) {
            pre0 = *(const float4*)(xl + (size_t)sA * 128 + f8);
            pre1 = *(const float4*)(xl + (size_t)sA * 128 + f8 + 4);
        }
        float e0 = x0.x + xrA.x; e0 = e0 > 0.f ? e0 : NEG_SLOPE * e0;
        float e1 = x0.y + xrA.y; e1 = e1 > 0.f ? e1 : NEG_SLOPE * e1;
        float e2 = x0.z + xrA.z; e2 = e2 > 0.f ? e2 : NEG_SLOPE * e2;
        float e3 = x0.w + xrA.w; e3 = e3 > 0.f ? e3 : NEG_SLOPE * e3;
        float e4 = x1.x + xrB.x; e4 = e4 > 0.f ? e4 : NEG_SLOPE * e4;
        float e5 = x1.y + xrB.y; e5 = e5 > 0.f ? e5 : NEG_SLOPE * e5;
        float e6 = x1.z + xrB.z; e6 = e6 > 0.f ? e6 : NEG_SLOPE * e6;
        float e7 = x1.w + xrB.w; e7 = e7 > 0.f ? e7 : NEG_SLOPE * e7;
        float q = e0 * atA.x + e1 * atA.y + e2 * atA.z + e3 * atA.w
                + e4 * atB.x + e5 * atB.y + e6 * atB.z + e7 * atB.w;
        q += __shfl_xor(q, 1); q += __shfl_xor(q, 2);
        float a = __expf(q);
        den += a;
        accA[0] = fmaf(a, x0.x, accA[0]); accA[1] = fmaf(a, x0.y, accA[1]);
        accA[2] = fmaf(a, x0.z, accA[2]); accA[3] = fmaf(a, x0.w, accA[3]);
        accB[0] = fmaf(a, x1.x, accB[0]); accB[1] = fmaf(a, x1.y, accB[1]);
        accB[2] = fmaf(a, x1.z, accB[2]); accB[3] = fmaf(a, x1.w, accB[3]);
    }

    // combine the four slots (xor 16, 32 preserve l16 -> same head)
    #pragma unroll
    for (int j = 0; j < 4; ++j) {
        accA[j] += __shfl_xor(accA[j], 16); accA[j] += __shfl_xor(accA[j], 32);
        accB[j] += __shfl_xor(accB[j], 16); accB[j] += __shfl_xor(accB[j], 32);
    }
    den += __shfl_xor(den, 16); den += __shfl_xor(den, 32);

    float inv = 1.0f / (den * (float)(end - start + 1));
    if (q4 == 0) {
        const float4 cbA = *(const float4*)(cb + f8);
        const float4 cbB = *(const float4*)(cb + f8 + 4);
        float4 oA, oB;
        oA.x = fmaf(accA[0], inv, cbA.x); oA.y = fmaf(accA[1], inv, cbA.y);
        oA.z = fmaf(accA[2], inv, cbA.z); oA.w = fmaf(accA[3], inv, cbA.w);
        oB.x = fmaf(accB[0], inv, cbB.x); oB.y = fmaf(accB[1], inv, cbB.y);
        oB.z = fmaf(accB[2], inv, cbB.z); oB.w = fmaf(accB[3], inv, cbB.w);
        *(float4*)&oslot[wid][f8]     = oA;
        *(float4*)&oslot[wid][f8 + 4] = oB;
    }
    asm volatile("s_waitcnt lgkmcnt(0)" ::: "memory");

    // fused linear: y[c] = sum_k o[k]*lw[c][k]; c=lane&31, k-range by half
    int half = lane >> 5;
    int l32 = lane & 31;
    float y = 0.f;
    int kbase = half * 64;
    #pragma unroll
    for (int k = 0; k < 64; k += 4) {
        float4 lv = *(const float4*)&lws[l32][kbase + k];
        float4 ov = *(const float4*)&oslot[wid][kbase + k];
        y = fmaf(lv.x, ov.x, y);
        y = fmaf(lv.y, ov.y, y);
        y = fmaf(lv.z, ov.z, y);
        y = fmaf(lv.w, ov.w, y);
    }
    y += __shfl_xor(y, 32);
    if (half == 0) out[(size_t)nd * 32 + l32] = y + lb[l32];
}

// ---------------------------------------------------------------------------
// global max pool over sorted batch ids (run-length + atomic flush)
// ---------------------------------------------------------------------------
__device__ __forceinline__ void atomicMaxFloat(float* addr, float val) {
    if (val >= 0.f) atomicMax((int*)addr, __float_as_int(val));
    else atomicMin((unsigned int*)addr, (unsigned int)__float_as_int(val));
}

__global__ void pool_kernel(const float* __restrict__ H, const int* __restrict__ batch,
                            float* __restrict__ g, int n) {
    int tid = threadIdx.x;
    int dim = tid & 31;
    int sub = tid >> 5;                 // 0..7
    int nodeStart = blockIdx.x * 128 + sub * 16;
    float m = -__builtin_inff();
    int cur = -1;
    for (int j = 0; j < 16; ++j) {
        int nd = nodeStart + j;
        if (nd >= n) break;
        int b = batch[nd];
        if (b != cur) {
            if (cur >= 0) atomicMaxFloat(&g[cur * 32 + dim], m);
            cur = b; m = -__builtin_inff();
        }
        m = fmaxf(m, H[nd * 32 + dim]);
    }
    if (cur >= 0) atomicMaxFloat(&g[cur * 32 + dim], m);
}

// ---------------------------------------------------------------------------
// final MLP: out = relu(g@fc1.T+b1) @ fc2.T + b2   (single block)
// ---------------------------------------------------------------------------
__global__ __launch_bounds__(256)
void fc_kernel(const float* __restrict__ g,
               const float* __restrict__ fc1W, const float* __restrict__ fc1b,
               const float* __restrict__ fc2W, const float* __restrict__ fc2b,
               float* __restrict__ out) {
    __shared__ float g1[GGRP * 32];
    int tid = threadIdx.x;
    for (int idx = tid; idx < GGRP * 32; idx += 256) {
        int r = idx >> 5, c = idx & 31;
        float acc = fc1b[c];
        #pragma unroll
        for (int k = 0; k < 32; ++k) acc = fmaf(g[r * 32 + k], fc1W[c * 32 + k], acc);
        g1[idx] = acc > 0.f ? acc : 0.f;
    }
    __syncthreads();
    for (int idx = tid; idx < GGRP * TOUT; idx += 256) {
        int r = idx / TOUT, c = idx - r * TOUT;
        float acc = fc2b[c];
        #pragma unroll
        for (int k = 0; k < 32; ++k) acc = fmaf(g1[r * 32 + k], fc2W[c * 32 + k], acc);
        out[idx] = acc;
    }
}

// ---------------------------------------------------------------------------
extern "C" void kernel_launch(void* const* d_in, const int* in_sizes, int n_in,
                              void* d_out, int out_size, void* d_ws, size_t ws_size,
                              hipStream_t stream) {
    const float* x     = (const float*)d_in[0];
    const int*   ei    = (const int*)d_in[1];     // [2][E]
    const int*   batch = (const int*)d_in[2];
    const float* Wl0 = (const float*)d_in[3];
    const float* bl0 = (const float*)d_in[4];
    const float* Wr0 = (const float*)d_in[5];
    const float* br0 = (const float*)d_in[6];
    const float* at0 = (const float*)d_in[7];
    const float* cb0 = (const float*)d_in[8];
    const float* lw0 = (const float*)d_in[9];
    const float* lb0 = (const float*)d_in[10];
    const float* Wl1 = (const float*)d_in[11];
    const float* bl1 = (const float*)d_in[12];
    const float* Wr1 = (const float*)d_in[13];
    const float* br1 = (const float*)d_in[14];
    const float* at1 = (const float*)d_in[15];
    const float* cb1 = (const float*)d_in[16];
    const float* lw1 = (const float*)d_in[17];
    const float* lb1 = (const float*)d_in[18];
    const float* fc1W = (const float*)d_in[19];
    const float* fc1b = (const float*)d_in[20];
    const float* fc2W = (const float*)d_in[21];
    const float* fc2b = (const float*)d_in[22];

    const int n = in_sizes[0] / 128;      // 30000
    const int E = in_sizes[1] / 2;        // 480000
    const int* src = ei;
    const int* dst = ei + E;
    const int nblkScan = (n + 255) / 256; // 118
    const int nRowBlk = (n + 127) / 128;  // 235

    // workspace layout
    size_t off = 0;
    auto alloc = [&](size_t bytes) {
        void* p = (char*)d_ws + off;
        off += (bytes + 255) & ~(size_t)255;
        return p;
    };
    float* xl    = (float*)alloc((size_t)n * 128 * 4);
    float* xr    = (float*)alloc((size_t)n * 128 * 4);
    float* hbuf  = (float*)alloc((size_t)n * 32 * 4);
    int* deg     = (int*)alloc((size_t)n * 4);
    int* rowptr  = (int*)alloc((size_t)(n + 1) * 4);
    int* cursor  = (int*)alloc((size_t)n * 4);
    int* csr     = (int*)alloc((size_t)E * 4);
    int* bsum    = (int*)alloc(128 * 4);
    int* boff    = (int*)alloc(128 * 4);
    float* gpool = (float*)alloc((size_t)GGRP * 32 * 4);

    // graph structure (shared by both convs)
    init_kernel<<<(n + 255) / 256, 256, 0, stream>>>(deg, gpool, n, GGRP * 32);
    degree_kernel<<<(E + 255) / 256, 256, 0, stream>>>(dst, deg, E);
    scanA_kernel<<<nblkScan, 256, 0, stream>>>(deg, rowptr, bsum, n);
    scanB_kernel<<<1, 64, 0, stream>>>(bsum, boff, rowptr, n, nblkScan);
    scanC_kernel<<<nblkScan, 256, 0, stream>>>(rowptr, cursor, boff, n);
    scatter_kernel<<<(E + 255) / 256, 256, 0, stream>>>(src, dst, cursor, csr, E);

    // conv 0 (fused conv+linear)
    gemm_tile_kernel<128><<<2 * nRowBlk, 256, 0, stream>>>(x, Wl0, bl0, Wr0, br0,
                                                           xl, xr, n, nRowBlk);
    gat_fused_kernel<<<(n + 3) / 4, 256, 0, stream>>>(xl, xr, at0, cb0, lw0, lb0,
                                                      rowptr, csr, hbuf, n);
    // conv 1
    gemm_tile_kernel<32><<<2 * nRowBlk, 256, 0, stream>>>(hbuf, Wl1, bl1, Wr1, br1,
                                                          xl, xr, n, nRowBlk);
    gat_fused_kernel<<<(n + 3) / 4, 256, 0, stream>>>(xl, xr, at1, cb1, lw1, lb1,
                                                      rowptr, csr, hbuf, n);

    // pool + MLP
    pool_kernel<<<(n + 127) / 128, 256, 0, stream>>>(hbuf, batch, gpool, n);
    fc_kernel<<<1, 256, 0, stream>>>(gpool, fc1W, fc1b, fc2W, fc2b, (float*)d_out);
}